// Round 8
// baseline (679.718 us; speedup 1.0000x reference)
//
#include <hip/hip_runtime.h>
#include <math.h>

#define NN 100000
#define FEAT 128
#define NHEAD 4
#define BSH 9                      // 512 nodes per bucket
#define BNODES 512
#define NBUCK 196                  // ceil(NN / 512)
#define BCAP 16384                 // colidx LDS image capacity (avg span ~8700)
#define PA_EPT 16                  // phase-A edges per thread
#define GTILES 6250                // 100000 / 16

typedef unsigned int uint;
typedef unsigned short ushort;
typedef __attribute__((ext_vector_type(8))) short short8;
typedef __attribute__((ext_vector_type(4))) float fx4;

__device__ __forceinline__ float lrelu(float v) { return v > 0.f ? v : 0.2f * v; }

__device__ __forceinline__ ushort f2bf(float f) {          // RNE bf16
    uint u = __float_as_uint(f);
    return (ushort)((u + 0x7fffu + ((u >> 16) & 1u)) >> 16);
}
__device__ __forceinline__ float bf_lo(uint u) { return __uint_as_float(u << 16); }
__device__ __forceinline__ float bf_hi(uint u) { return __uint_as_float(u & 0xffff0000u); }

// ---- fp32 -> bf16 convert (layer-0 input) ----
__global__ __launch_bounds__(256) void convert_bf_kernel(
    const float* __restrict__ x, ushort* __restrict__ xbf)
{
    int i = blockIdx.x * 256 + threadIdx.x;
    if (i >= NN * FEAT / 4) return;
    float4 v = ((const float4*)x)[i];
    ushort4 u;
    u.x = f2bf(v.x); u.y = f2bf(v.y); u.z = f2bf(v.z); u.w = f2bf(v.w);
    ((ushort4*)xbf)[i] = u;
}

// ---- MFMA GEMM: h(bf16) = in(bf16) @ W, + per-node logits al_src/al_dst ----
// A-frags stay in LDS (read at use); B for next tile prefetched during MFMAs.
// __launch_bounds__(256,4): VGPR<=128 -> 4 blocks/CU (16 waves/CU).
__global__ __launch_bounds__(256, 4) void gemm_mfma_kernel(
    const ushort* __restrict__ inbf, const float* __restrict__ W,
    const float* __restrict__ a_src, const float* __restrict__ a_dst,
    ushort* __restrict__ hbf, float* __restrict__ al_s, float* __restrict__ al_d)
{
    __shared__ __align__(16) ushort WA[FEAT * FEAT];   // 32 KiB, fragment-ordered
    const int t = threadIdx.x;
    const int wv = t >> 6, lane = t & 63;
    // stage W: each thread builds short8 frags -> ds_write_b128
    {
        int ln = lane;
        int mm15 = ln & 15, qq = ln >> 4;
        for (int f = wv; f < 32; f += 4) {
            int mt = f >> 2, kt = f & 3;
            int m = mt * 16 + mm15;
            int kb = kt * 32 + qq * 8;
            short8 v;
            #pragma unroll
            for (int j = 0; j < 8; ++j)
                v[j] = (short)f2bf(W[(kb + j) * FEAT + m]);
            *(short8*)&WA[(f * 64 + ln) * 8] = v;
        }
    }
    __syncthreads();

    const int node_l = lane & 15, q = lane >> 4;
    const int stride = gridDim.x * 4;

    int tile = blockIdx.x * 4 + wv;
    if (tile >= GTILES) return;

    // load B for first tile
    const ushort* rowp = inbf + (size_t)(tile * 16 + node_l) * FEAT + q * 8;
    short8 b0 = *(const short8*)(rowp);
    short8 b1 = *(const short8*)(rowp + 32);
    short8 b2 = *(const short8*)(rowp + 64);
    short8 b3 = *(const short8*)(rowp + 96);

    for (; tile < GTILES; tile += stride) {
        const int n0 = tile * 16;
        int ntile = tile + stride;
        short8 nb0, nb1, nb2, nb3;
        if (ntile < GTILES) {
            const ushort* nrp = inbf + (size_t)(ntile * 16 + node_l) * FEAT + q * 8;
            nb0 = *(const short8*)(nrp);
            nb1 = *(const short8*)(nrp + 32);
            nb2 = *(const short8*)(nrp + 64);
            nb3 = *(const short8*)(nrp + 96);
        }
        fx4 zero = {0.f, 0.f, 0.f, 0.f};
        fx4 acc[8];
        #pragma unroll
        for (int mt = 0; mt < 8; ++mt) acc[mt] = zero;
        #pragma unroll
        for (int kt = 0; kt < 4; ++kt) {
            short8 b = (kt == 0) ? b0 : (kt == 1) ? b1 : (kt == 2) ? b2 : b3;
            #pragma unroll
            for (int mt = 0; mt < 8; ++mt) {
                short8 a = *(const short8*)&WA[((mt * 4 + kt) * 64 + lane) * 8];
                acc[mt] = __builtin_amdgcn_mfma_f32_16x16x32_bf16(a, b, acc[mt], 0, 0, 0);
            }
        }
        // epilogue: h store (bf16) + logit partials
        float ps[4] = {0.f, 0.f, 0.f, 0.f};
        float pd[4] = {0.f, 0.f, 0.f, 0.f};
        #pragma unroll
        for (int mt = 0; mt < 8; ++mt) {
            float4 as4 = *(const float4*)(a_src + mt * 16 + q * 4);
            float4 ad4 = *(const float4*)(a_dst + mt * 16 + q * 4);
            ps[mt >> 1] += acc[mt][0] * as4.x + acc[mt][1] * as4.y + acc[mt][2] * as4.z + acc[mt][3] * as4.w;
            pd[mt >> 1] += acc[mt][0] * ad4.x + acc[mt][1] * ad4.y + acc[mt][2] * ad4.z + acc[mt][3] * ad4.w;
            ushort4 hv;
            hv.x = f2bf(acc[mt][0]); hv.y = f2bf(acc[mt][1]);
            hv.z = f2bf(acc[mt][2]); hv.w = f2bf(acc[mt][3]);
            *(ushort4*)(hbf + (size_t)(n0 + node_l) * FEAT + mt * 16 + q * 4) = hv;
        }
        #pragma unroll
        for (int h = 0; h < 4; ++h) {
            ps[h] += __shfl_xor(ps[h], 16); ps[h] += __shfl_xor(ps[h], 32);
            pd[h] += __shfl_xor(pd[h], 16); pd[h] += __shfl_xor(pd[h], 32);
        }
        float vs = (q == 0) ? ps[0] : (q == 1) ? ps[1] : (q == 2) ? ps[2] : ps[3];
        float vd = (q == 0) ? pd[0] : (q == 1) ? pd[1] : (q == 2) ? pd[2] : pd[3];
        al_s[(n0 + node_l) * 4 + q] = vs;
        al_d[(n0 + node_l) * 4 + q] = vd;
        b0 = nb0; b1 = nb1; b2 = nb2; b3 = nb3;
    }
}

// ======================= CSR build: bucketed counting sort =======================

__global__ void zero_small_kernel(int* bsize)
{
    int t = threadIdx.x;
    if (t < NBUCK) bsize[t] = 0;
}

__global__ __launch_bounds__(256) void bucket_hist_kernel(
    const int* __restrict__ ei, int E, int* bsize)
{
    __shared__ int lh[NBUCK];
    int t = threadIdx.x;
    if (t < NBUCK) lh[t] = 0;
    __syncthreads();
    int stride = gridDim.x * 256;
    for (int i = blockIdx.x * 256 + t; i < E + NN; i += stride) {
        int d = (i < E) ? ei[E + i] : (i - E);
        atomicAdd(&lh[d >> BSH], 1);
    }
    __syncthreads();
    if (t < NBUCK && lh[t]) atomicAdd(&bsize[t], lh[t]);
}

__global__ void bucket_scan_kernel(const int* __restrict__ bsize, int* bbase, int* bcursor)
{
    if (threadIdx.x == 0) {
        int acc = 0;
        for (int b = 0; b < NBUCK; ++b) { bbase[b] = acc; bcursor[b] = acc; acc += bsize[b]; }
        bbase[NBUCK] = acc;
    }
}

__global__ __launch_bounds__(256) void phaseA_bin_kernel(
    const int* __restrict__ ei, int E, int* bcursor, int2* __restrict__ pairs)
{
    __shared__ int lh[NBUCK], lb[NBUCK];
    int t = threadIdx.x;
    if (t < NBUCK) lh[t] = 0;
    __syncthreads();
    int base = blockIdx.x * (256 * PA_EPT) + t;
    int s[PA_EPT], d[PA_EPT];
    #pragma unroll
    for (int k = 0; k < PA_EPT; ++k) {
        int i = base + k * 256;
        if (i < E)            { s[k] = ei[i]; d[k] = ei[E + i]; }
        else if (i < E + NN)  { s[k] = i - E; d[k] = s[k]; }
        else                  { s[k] = 0; d[k] = -1; }
        if (d[k] >= 0) atomicAdd(&lh[d[k] >> BSH], 1);
    }
    __syncthreads();
    if (t < NBUCK) {
        int c = lh[t];
        lb[t] = c ? atomicAdd(&bcursor[t], c) : 0;
        lh[t] = 0;
    }
    __syncthreads();
    #pragma unroll
    for (int k = 0; k < PA_EPT; ++k) {
        if (d[k] >= 0) {
            int b = d[k] >> BSH;
            int off = atomicAdd(&lh[b], 1);
            pairs[lb[b] + off] = make_int2(d[k], s[k]);
        }
    }
}

__global__ __launch_bounds__(256) void phaseB_kernel(
    const int2* __restrict__ pairs, const int* __restrict__ bbase,
    int* __restrict__ row_ptr, int* __restrict__ colidx, int EP)
{
    __shared__ int nh[BNODES];
    __shared__ int ex[BNODES];
    __shared__ int ss[256];
    __shared__ int img[BCAP];
    int b = blockIdx.x, t = threadIdx.x;
    int node0 = b << BSH;
    int nend = min(NN - node0, BNODES);
    int pb = bbase[b], pe = bbase[b + 1];
    int span = pe - pb;
    for (int j = t; j < BNODES; j += 256) nh[j] = 0;
    __syncthreads();
    for (int i = t; i < span; i += 256)
        atomicAdd(&nh[pairs[pb + i].x - node0], 1);
    __syncthreads();
    int v0 = nh[2 * t], v1 = nh[2 * t + 1];
    int psc = v0 + v1;
    ss[t] = psc;
    __syncthreads();
    #pragma unroll
    for (int off = 1; off < 256; off <<= 1) {
        int x = (t >= off) ? ss[t - off] : 0;
        __syncthreads();
        ss[t] += x;
        __syncthreads();
    }
    int ep = ss[t] - psc;
    ex[2 * t] = ep;
    ex[2 * t + 1] = ep + v0;
    __syncthreads();
    for (int j = t; j < nend; j += 256) row_ptr[node0 + j] = pb + ex[j];
    if (b == NBUCK - 1 && t == 0) row_ptr[NN] = EP;
    for (int j = t; j < BNODES; j += 256) nh[j] = ex[j];   // reuse as cursors
    __syncthreads();
    if (span <= BCAP) {
        for (int i = t; i < span; i += 256) {
            int2 p = pairs[pb + i];
            int pos = atomicAdd(&nh[p.x - node0], 1);
            img[pos] = p.y;
        }
        __syncthreads();
        for (int i = t; i < span; i += 256) colidx[pb + i] = img[i];
    } else {
        for (int i = t; i < span; i += 256) {
            int2 p = pairs[pb + i];
            int pos = atomicAdd(&nh[p.x - node0], 1);
            colidx[pb + pos] = p.y;
        }
    }
}

// ======================= fused softmax + aggregation (bf16 out) =======================
#define AGGR_STEP(hv, wgt)                                                    \
    a0 = fmaf(wgt, bf_lo(hv.x), a0); a1 = fmaf(wgt, bf_hi(hv.x), a1);        \
    a2 = fmaf(wgt, bf_lo(hv.y), a2); a3 = fmaf(wgt, bf_hi(hv.y), a3);        \
    a4 = fmaf(wgt, bf_lo(hv.z), a4); a5 = fmaf(wgt, bf_hi(hv.z), a5);        \
    a6 = fmaf(wgt, bf_lo(hv.w), a6); a7 = fmaf(wgt, bf_hi(hv.w), a7);

// process one prefetched int4 batch of 4 edges
#define PROC4(cv)                                                             \
    {                                                                         \
        int s0 = cv.x, s1 = cv.y, s2 = cv.z, s3 = cv.w;                       \
        float w0 = __expf(lrelu(al_s[s0*4 + head] + ald_h));                  \
        float w1 = __expf(lrelu(al_s[s1*4 + head] + ald_h));                  \
        float w2 = __expf(lrelu(al_s[s2*4 + head] + ald_h));                  \
        float w3 = __expf(lrelu(al_s[s3*4 + head] + ald_h));                  \
        uint4 h0 = ((const uint4*)(hbf + (size_t)s0 * FEAT))[lane];           \
        uint4 h1 = ((const uint4*)(hbf + (size_t)s1 * FEAT))[lane];           \
        uint4 h2 = ((const uint4*)(hbf + (size_t)s2 * FEAT))[lane];           \
        uint4 h3 = ((const uint4*)(hbf + (size_t)s3 * FEAT))[lane];           \
        ssum += (w0 + w1) + (w2 + w3);                                        \
        AGGR_STEP(h0, w0) AGGR_STEP(h1, w1) AGGR_STEP(h2, w2) AGGR_STEP(h3, w3) \
    }

__global__ __launch_bounds__(256) void aggr_csr_kernel(
    const int* __restrict__ row_ptr, const int* __restrict__ colidx,
    const ushort* __restrict__ hbf, const float* __restrict__ al_s,
    const float* __restrict__ al_d, const float* __restrict__ bias,
    ushort* __restrict__ outbf)
{
    int t = threadIdx.x;
    int node = blockIdx.x * 16 + (t >> 4);
    if (node >= NN) return;
    int lane = t & 15;
    int head = lane >> 2;
    float ald_h = al_d[node * 4 + head];
    int beg = row_ptr[node], end = row_ptr[node + 1];

    float ssum = 0.f;
    float a0=0.f,a1=0.f,a2=0.f,a3=0.f,a4=0.f,a5=0.f,a6=0.f,a7=0.f;

    int p = beg;
    int4 ca;
    if (p + 4 <= end) ca = *(const int4*)&colidx[p];
    while (p + 8 <= end) {
        int4 na = *(const int4*)&colidx[p + 4];   // prefetch next batch
        PROC4(ca)
        ca = na;
        p += 4;
    }
    if (p + 4 <= end) { PROC4(ca) p += 4; }
    for (; p < end; ++p) {
        int sn = colidx[p];
        float wq = __expf(lrelu(al_s[sn*4 + head] + ald_h));
        uint4 hv = ((const uint4*)(hbf + (size_t)sn * FEAT))[lane];
        ssum += wq;
        AGGR_STEP(hv, wq)
    }
    float inv = 1.f / (ssum + 1e-16f);
    const float* bp = bias + lane * 8;
    float o[8] = {a0,a1,a2,a3,a4,a5,a6,a7};
    #pragma unroll
    for (int k = 0; k < 8; ++k) {
        float v = o[k] * inv + bp[k];
        o[k] = v > 0.f ? v : __expf(v) - 1.f;
    }
    uint4 u;
    u.x = (uint)f2bf(o[0]) | ((uint)f2bf(o[1]) << 16);
    u.y = (uint)f2bf(o[2]) | ((uint)f2bf(o[3]) << 16);
    u.z = (uint)f2bf(o[4]) | ((uint)f2bf(o[5]) << 16);
    u.w = (uint)f2bf(o[6]) | ((uint)f2bf(o[7]) << 16);
    ((uint4*)(outbf + (size_t)node * FEAT))[lane] = u;
}

// ---- final FC (128 -> 10, bf16 in) + log_softmax; THREAD per node ----
__global__ __launch_bounds__(256) void fc_kernel(
    const ushort* __restrict__ hbf, const float* __restrict__ fcW,
    const float* __restrict__ fcb, float* __restrict__ out)
{
    __shared__ float WT[10][FEAT];   // 5 KiB
    __shared__ float bl[10];
    int t = threadIdx.x;
    for (int i = t; i < FEAT * 10; i += 256) {
        int k = i / 10, c = i % 10;
        WT[c][k] = fcW[i];
    }
    if (t < 10) bl[t] = fcb[t];
    __syncthreads();
    int n = blockIdx.x * 256 + t;
    if (n >= NN) return;
    const uint4* row = (const uint4*)(hbf + (size_t)n * FEAT);
    float lg[10];
    #pragma unroll
    for (int c = 0; c < 10; ++c) lg[c] = bl[c];
    #pragma unroll 4
    for (int k8 = 0; k8 < 16; ++k8) {
        uint4 u = row[k8];
        float x0 = bf_lo(u.x), x1 = bf_hi(u.x), x2 = bf_lo(u.y), x3 = bf_hi(u.y);
        float x4 = bf_lo(u.z), x5 = bf_hi(u.z), x6 = bf_lo(u.w), x7 = bf_hi(u.w);
        #pragma unroll
        for (int c = 0; c < 10; ++c) {
            const float* wr = &WT[c][k8 * 8];
            float4 wa = *(const float4*)(wr);
            float4 wb = *(const float4*)(wr + 4);
            float acc = fmaf(x0, wa.x, fmaf(x1, wa.y, fmaf(x2, wa.z, x3 * wa.w)));
            acc = fmaf(x4, wb.x, fmaf(x5, wb.y, fmaf(x6, wb.z, fmaf(x7, wb.w, acc))));
            lg[c] += acc;
        }
    }
    float mx = lg[0];
    #pragma unroll
    for (int c = 1; c < 10; ++c) mx = fmaxf(mx, lg[c]);
    float se = 0.f;
    #pragma unroll
    for (int c = 0; c < 10; ++c) se += __expf(lg[c] - mx);
    float lse = mx + __logf(se);
    float2* op = (float2*)(out + (size_t)n * 10);
    #pragma unroll
    for (int c = 0; c < 5; ++c)
        op[c] = make_float2(lg[2*c] - lse, lg[2*c + 1] - lse);
}

extern "C" void kernel_launch(void* const* d_in, const int* in_sizes, int n_in,
                              void* d_out, int out_size, void* d_ws, size_t ws_size,
                              hipStream_t stream)
{
    const float* x   = (const float*)d_in[0];
    const int*   ei  = (const int*)d_in[1];
    const float* W[3]   = {(const float*)d_in[2], (const float*)d_in[6],  (const float*)d_in[10]};
    const float* asr[3] = {(const float*)d_in[3], (const float*)d_in[7],  (const float*)d_in[11]};
    const float* ads[3] = {(const float*)d_in[4], (const float*)d_in[8],  (const float*)d_in[12]};
    const float* bs[3]  = {(const float*)d_in[5], (const float*)d_in[9],  (const float*)d_in[13]};
    const float* fcW = (const float*)d_in[14];
    const float* fcb = (const float*)d_in[15];
    const int E  = in_sizes[1] / 2;
    const int EP = E + NN;

    // workspace layout
    ushort* xbf  = (ushort*)d_ws;                      // [NN*FEAT] bf16 (layer-0 in)
    ushort* hbf  = xbf + (size_t)NN * FEAT;            // [NN*FEAT] bf16 (gemm out)
    ushort* ybf  = hbf + (size_t)NN * FEAT;            // [NN*FEAT] bf16 (aggr out)
    float* als   = (float*)(ybf + (size_t)NN * FEAT);  // [NN*4]
    float* ald   = als + (size_t)NN * NHEAD;           // [NN*4]
    int* row_ptr = (int*)(ald + (size_t)NN * NHEAD);   // [NN+1]
    int* bsize   = row_ptr + NN + 1;                   // [NBUCK]
    int* bbase   = bsize + NBUCK;                      // [NBUCK+1]
    int* bcursor = bbase + NBUCK + 1;                  // [NBUCK]
    int2* pairs  = (int2*)(bcursor + NBUCK);           // [EP]
    int* colidx  = (int*)(pairs + (size_t)EP);         // [EP]

    // ---- CSR build (once; graph is layer-invariant) ----
    zero_small_kernel<<<1, 256, 0, stream>>>(bsize);
    bucket_hist_kernel<<<1024, 256, 0, stream>>>(ei, E, bsize);
    bucket_scan_kernel<<<1, 64, 0, stream>>>(bsize, bbase, bcursor);
    phaseA_bin_kernel<<<(EP + 256*PA_EPT - 1) / (256*PA_EPT), 256, 0, stream>>>(ei, E, bcursor, pairs);
    phaseB_kernel<<<NBUCK, 256, 0, stream>>>(pairs, bbase, row_ptr, colidx, EP);

    convert_bf_kernel<<<(NN * FEAT / 4 + 255) / 256, 256, 0, stream>>>(x, xbf);

    const ushort* fin = xbf;
    for (int l = 0; l < 3; ++l) {
        gemm_mfma_kernel<<<1024, 256, 0, stream>>>(fin, W[l], asr[l], ads[l], hbf, als, ald);
        aggr_csr_kernel<<<(NN + 15) / 16, 256, 0, stream>>>(row_ptr, colidx, hbf, als, ald, bs[l], ybf);
        fin = ybf;
    }
    fc_kernel<<<(NN + 255) / 256, 256, 0, stream>>>(ybf, fcW, fcb, (float*)d_out);
}

// Round 9
// 502.410 us; speedup vs baseline: 1.3529x; 1.3529x over previous
//
#include <hip/hip_runtime.h>
#include <math.h>

#define NN 100000
#define FEAT 128
#define NHEAD 4
#define BSH 9                      // 512 nodes per bucket
#define BNODES 512
#define NBUCK 196                  // ceil(NN / 512)
#define BCAP 16384                 // colidx LDS image capacity (avg span ~8700)
#define PA_EPT 16                  // phase-A edges per thread
#define GTILES 6250                // 100000 / 16
#define HSTRIDE 136                // h-staging row stride (ushorts): 272B = 16B-aligned, bank-rotated

typedef unsigned int uint;
typedef unsigned short ushort;
typedef __attribute__((ext_vector_type(8))) short short8;
typedef __attribute__((ext_vector_type(4))) float fx4;

__device__ __forceinline__ float lrelu(float v) { return v > 0.f ? v : 0.2f * v; }

__device__ __forceinline__ ushort f2bf(float f) {          // RNE bf16
    uint u = __float_as_uint(f);
    return (ushort)((u + 0x7fffu + ((u >> 16) & 1u)) >> 16);
}
__device__ __forceinline__ float bf_lo(uint u) { return __uint_as_float(u << 16); }
__device__ __forceinline__ float bf_hi(uint u) { return __uint_as_float(u & 0xffff0000u); }

// ---- fp32 -> bf16 convert (layer-0 input) ----
__global__ __launch_bounds__(256) void convert_bf_kernel(
    const float* __restrict__ x, ushort* __restrict__ xbf)
{
    int i = blockIdx.x * 256 + threadIdx.x;
    if (i >= NN * FEAT / 4) return;
    float4 v = ((const float4*)x)[i];
    ushort4 u;
    u.x = f2bf(v.x); u.y = f2bf(v.y); u.z = f2bf(v.z); u.w = f2bf(v.w);
    ((ushort4*)xbf)[i] = u;
}

// ---- MFMA GEMM: h(bf16) = in(bf16) @ W, + per-node logits al_src/al_dst ----
// A = W^T cached in VGPRs (round-7 structure). NEW: h stores staged through a
// per-wave LDS tile so global writes are full-line contiguous (1 KB/instr) --
// the direct 8B/lane D-layout stores caused 7x write amplification (r8 PMC).
__global__ __launch_bounds__(256, 2) void gemm_mfma_kernel(
    const ushort* __restrict__ inbf, const float* __restrict__ W,
    const float* __restrict__ a_src, const float* __restrict__ a_dst,
    ushort* __restrict__ hbf, float* __restrict__ al_s, float* __restrict__ al_d)
{
    __shared__ __align__(16) ushort WA[FEAT * FEAT];       // 32 KiB, fragment-ordered
    __shared__ __align__(16) ushort HS[4][16 * HSTRIDE];   // 17 KiB, per-wave h staging
    const int t = threadIdx.x;
    for (int idx = t; idx < FEAT * FEAT; idx += 256) {
        int k = idx >> 7, m = idx & 127;
        int mt = m >> 4, kt = k >> 5, qq = (k >> 3) & 3, j = k & 7;
        int ln = qq * 16 + (m & 15);
        WA[((mt * 4 + kt) * 64 + ln) * 8 + j] = f2bf(W[idx]);
    }
    __syncthreads();

    const int wv = t >> 6, lane = t & 63;
    const int node_l = lane & 15, q = lane >> 4;

    short8 afr[8][4];
    #pragma unroll
    for (int mt = 0; mt < 8; ++mt)
        #pragma unroll
        for (int kt = 0; kt < 4; ++kt)
            afr[mt][kt] = *(const short8*)&WA[((mt * 4 + kt) * 64 + lane) * 8];

    for (int tile = blockIdx.x * 4 + wv; tile < GTILES; tile += gridDim.x * 4) {
        const int n0 = tile * 16;
        const ushort* rowp = inbf + (size_t)(n0 + node_l) * FEAT + q * 8;
        short8 b0 = *(const short8*)(rowp);
        short8 b1 = *(const short8*)(rowp + 32);
        short8 b2 = *(const short8*)(rowp + 64);
        short8 b3 = *(const short8*)(rowp + 96);
        fx4 zero = {0.f, 0.f, 0.f, 0.f};
        fx4 acc[8];
        #pragma unroll
        for (int mt = 0; mt < 8; ++mt) acc[mt] = zero;
        #pragma unroll
        for (int kt = 0; kt < 4; ++kt) {
            short8 b = (kt == 0) ? b0 : (kt == 1) ? b1 : (kt == 2) ? b2 : b3;
            #pragma unroll
            for (int mt = 0; mt < 8; ++mt)
                acc[mt] = __builtin_amdgcn_mfma_f32_16x16x32_bf16(afr[mt][kt], b, acc[mt], 0, 0, 0);
        }
        // epilogue: logits + stage h into per-wave LDS tile
        float ps[4] = {0.f, 0.f, 0.f, 0.f};
        float pd[4] = {0.f, 0.f, 0.f, 0.f};
        #pragma unroll
        for (int mt = 0; mt < 8; ++mt) {
            float4 as4 = *(const float4*)(a_src + mt * 16 + q * 4);
            float4 ad4 = *(const float4*)(a_dst + mt * 16 + q * 4);
            ps[mt >> 1] += acc[mt][0] * as4.x + acc[mt][1] * as4.y + acc[mt][2] * as4.z + acc[mt][3] * as4.w;
            pd[mt >> 1] += acc[mt][0] * ad4.x + acc[mt][1] * ad4.y + acc[mt][2] * ad4.z + acc[mt][3] * ad4.w;
            ushort4 hv;
            hv.x = f2bf(acc[mt][0]); hv.y = f2bf(acc[mt][1]);
            hv.z = f2bf(acc[mt][2]); hv.w = f2bf(acc[mt][3]);
            *(ushort4*)&HS[wv][node_l * HSTRIDE + mt * 16 + q * 4] = hv;
        }
        #pragma unroll
        for (int h = 0; h < 4; ++h) {
            ps[h] += __shfl_xor(ps[h], 16); ps[h] += __shfl_xor(ps[h], 32);
            pd[h] += __shfl_xor(pd[h], 16); pd[h] += __shfl_xor(pd[h], 32);
        }
        float vs = (q == 0) ? ps[0] : (q == 1) ? ps[1] : (q == 2) ? ps[2] : ps[3];
        float vd = (q == 0) ? pd[0] : (q == 1) ? pd[1] : (q == 2) ? pd[2] : pd[3];
        al_s[(n0 + node_l) * 4 + q] = vs;
        al_d[(n0 + node_l) * 4 + q] = vd;
        // copy-out: wave-private LDS -> 4x fully-coalesced 1KB global stores
        #pragma unroll
        for (int it = 0; it < 4; ++it) {
            int fi = it * 64 + lane;               // 16B chunk index within tile
            int row = fi >> 4, colc = fi & 15;
            short8 v = *(const short8*)&HS[wv][row * HSTRIDE + colc * 8];
            *(short8*)(hbf + (size_t)n0 * FEAT + (size_t)fi * 8) = v;
        }
    }
}

// ======================= CSR build: bucketed counting sort =======================

__global__ void zero_small_kernel(int* bsize)
{
    int t = threadIdx.x;
    if (t < NBUCK) bsize[t] = 0;
}

__global__ __launch_bounds__(256) void bucket_hist_kernel(
    const int* __restrict__ ei, int E, int* bsize)
{
    __shared__ int lh[NBUCK];
    int t = threadIdx.x;
    if (t < NBUCK) lh[t] = 0;
    __syncthreads();
    int stride = gridDim.x * 256;
    for (int i = blockIdx.x * 256 + t; i < E + NN; i += stride) {
        int d = (i < E) ? ei[E + i] : (i - E);
        atomicAdd(&lh[d >> BSH], 1);
    }
    __syncthreads();
    if (t < NBUCK && lh[t]) atomicAdd(&bsize[t], lh[t]);
}

__global__ void bucket_scan_kernel(const int* __restrict__ bsize, int* bbase, int* bcursor)
{
    if (threadIdx.x == 0) {
        int acc = 0;
        for (int b = 0; b < NBUCK; ++b) { bbase[b] = acc; bcursor[b] = acc; acc += bsize[b]; }
        bbase[NBUCK] = acc;
    }
}

__global__ __launch_bounds__(256) void phaseA_bin_kernel(
    const int* __restrict__ ei, int E, int* bcursor, int2* __restrict__ pairs)
{
    __shared__ int lh[NBUCK], lb[NBUCK];
    int t = threadIdx.x;
    if (t < NBUCK) lh[t] = 0;
    __syncthreads();
    int base = blockIdx.x * (256 * PA_EPT) + t;
    int s[PA_EPT], d[PA_EPT];
    #pragma unroll
    for (int k = 0; k < PA_EPT; ++k) {
        int i = base + k * 256;
        if (i < E)            { s[k] = ei[i]; d[k] = ei[E + i]; }
        else if (i < E + NN)  { s[k] = i - E; d[k] = s[k]; }
        else                  { s[k] = 0; d[k] = -1; }
        if (d[k] >= 0) atomicAdd(&lh[d[k] >> BSH], 1);
    }
    __syncthreads();
    if (t < NBUCK) {
        int c = lh[t];
        lb[t] = c ? atomicAdd(&bcursor[t], c) : 0;
        lh[t] = 0;
    }
    __syncthreads();
    #pragma unroll
    for (int k = 0; k < PA_EPT; ++k) {
        if (d[k] >= 0) {
            int b = d[k] >> BSH;
            int off = atomicAdd(&lh[b], 1);
            pairs[lb[b] + off] = make_int2(d[k], s[k]);
        }
    }
}

__global__ __launch_bounds__(256) void phaseB_kernel(
    const int2* __restrict__ pairs, const int* __restrict__ bbase,
    int* __restrict__ row_ptr, int* __restrict__ colidx, int EP)
{
    __shared__ int nh[BNODES];
    __shared__ int ex[BNODES];
    __shared__ int ss[256];
    __shared__ int img[BCAP];
    int b = blockIdx.x, t = threadIdx.x;
    int node0 = b << BSH;
    int nend = min(NN - node0, BNODES);
    int pb = bbase[b], pe = bbase[b + 1];
    int span = pe - pb;
    for (int j = t; j < BNODES; j += 256) nh[j] = 0;
    __syncthreads();
    for (int i = t; i < span; i += 256)
        atomicAdd(&nh[pairs[pb + i].x - node0], 1);
    __syncthreads();
    int v0 = nh[2 * t], v1 = nh[2 * t + 1];
    int psc = v0 + v1;
    ss[t] = psc;
    __syncthreads();
    #pragma unroll
    for (int off = 1; off < 256; off <<= 1) {
        int x = (t >= off) ? ss[t - off] : 0;
        __syncthreads();
        ss[t] += x;
        __syncthreads();
    }
    int ep = ss[t] - psc;
    ex[2 * t] = ep;
    ex[2 * t + 1] = ep + v0;
    __syncthreads();
    for (int j = t; j < nend; j += 256) row_ptr[node0 + j] = pb + ex[j];
    if (b == NBUCK - 1 && t == 0) row_ptr[NN] = EP;
    for (int j = t; j < BNODES; j += 256) nh[j] = ex[j];   // reuse as cursors
    __syncthreads();
    if (span <= BCAP) {
        for (int i = t; i < span; i += 256) {
            int2 p = pairs[pb + i];
            int pos = atomicAdd(&nh[p.x - node0], 1);
            img[pos] = p.y;
        }
        __syncthreads();
        for (int i = t; i < span; i += 256) colidx[pb + i] = img[i];
    } else {
        for (int i = t; i < span; i += 256) {
            int2 p = pairs[pb + i];
            int pos = atomicAdd(&nh[p.x - node0], 1);
            colidx[pb + pos] = p.y;
        }
    }
}

// ======================= fused softmax + aggregation (bf16 out) =======================
#define AGGR_STEP(hv, wgt)                                                    \
    a0 = fmaf(wgt, bf_lo(hv.x), a0); a1 = fmaf(wgt, bf_hi(hv.x), a1);        \
    a2 = fmaf(wgt, bf_lo(hv.y), a2); a3 = fmaf(wgt, bf_hi(hv.y), a3);        \
    a4 = fmaf(wgt, bf_lo(hv.z), a4); a5 = fmaf(wgt, bf_hi(hv.z), a5);        \
    a6 = fmaf(wgt, bf_lo(hv.w), a6); a7 = fmaf(wgt, bf_hi(hv.w), a7);

#define PROC4(cv)                                                             \
    {                                                                         \
        int s0 = cv.x, s1 = cv.y, s2 = cv.z, s3 = cv.w;                       \
        float w0 = __expf(lrelu(al_s[s0*4 + head] + ald_h));                  \
        float w1 = __expf(lrelu(al_s[s1*4 + head] + ald_h));                  \
        float w2 = __expf(lrelu(al_s[s2*4 + head] + ald_h));                  \
        float w3 = __expf(lrelu(al_s[s3*4 + head] + ald_h));                  \
        uint4 h0 = ((const uint4*)(hbf + (size_t)s0 * FEAT))[lane];           \
        uint4 h1 = ((const uint4*)(hbf + (size_t)s1 * FEAT))[lane];           \
        uint4 h2 = ((const uint4*)(hbf + (size_t)s2 * FEAT))[lane];           \
        uint4 h3 = ((const uint4*)(hbf + (size_t)s3 * FEAT))[lane];           \
        ssum += (w0 + w1) + (w2 + w3);                                        \
        AGGR_STEP(h0, w0) AGGR_STEP(h1, w1) AGGR_STEP(h2, w2) AGGR_STEP(h3, w3) \
    }

__global__ __launch_bounds__(256) void aggr_csr_kernel(
    const int* __restrict__ row_ptr, const int* __restrict__ colidx,
    const ushort* __restrict__ hbf, const float* __restrict__ al_s,
    const float* __restrict__ al_d, const float* __restrict__ bias,
    ushort* __restrict__ outbf)
{
    int t = threadIdx.x;
    int node = blockIdx.x * 16 + (t >> 4);
    if (node >= NN) return;
    int lane = t & 15;
    int head = lane >> 2;
    float ald_h = al_d[node * 4 + head];
    int beg = row_ptr[node], end = row_ptr[node + 1];

    float ssum = 0.f;
    float a0=0.f,a1=0.f,a2=0.f,a3=0.f,a4=0.f,a5=0.f,a6=0.f,a7=0.f;

    int p = beg;
    int4 ca;
    if (p + 4 <= end) ca = *(const int4*)&colidx[p];
    while (p + 8 <= end) {
        int4 na = *(const int4*)&colidx[p + 4];   // prefetch next batch
        PROC4(ca)
        ca = na;
        p += 4;
    }
    if (p + 4 <= end) { PROC4(ca) p += 4; }
    for (; p < end; ++p) {
        int sn = colidx[p];
        float wq = __expf(lrelu(al_s[sn*4 + head] + ald_h));
        uint4 hv = ((const uint4*)(hbf + (size_t)sn * FEAT))[lane];
        ssum += wq;
        AGGR_STEP(hv, wq)
    }
    float inv = 1.f / (ssum + 1e-16f);
    const float* bp = bias + lane * 8;
    float o[8] = {a0,a1,a2,a3,a4,a5,a6,a7};
    #pragma unroll
    for (int k = 0; k < 8; ++k) {
        float v = o[k] * inv + bp[k];
        o[k] = v > 0.f ? v : __expf(v) - 1.f;
    }
    uint4 u;
    u.x = (uint)f2bf(o[0]) | ((uint)f2bf(o[1]) << 16);
    u.y = (uint)f2bf(o[2]) | ((uint)f2bf(o[3]) << 16);
    u.z = (uint)f2bf(o[4]) | ((uint)f2bf(o[5]) << 16);
    u.w = (uint)f2bf(o[6]) | ((uint)f2bf(o[7]) << 16);
    ((uint4*)(outbf + (size_t)node * FEAT))[lane] = u;
}

// ---- final FC (128 -> 10, bf16 in) + log_softmax; THREAD per node ----
__global__ __launch_bounds__(256) void fc_kernel(
    const ushort* __restrict__ hbf, const float* __restrict__ fcW,
    const float* __restrict__ fcb, float* __restrict__ out)
{
    __shared__ float WT[10][FEAT];   // 5 KiB
    __shared__ float bl[10];
    int t = threadIdx.x;
    for (int i = t; i < FEAT * 10; i += 256) {
        int k = i / 10, c = i % 10;
        WT[c][k] = fcW[i];
    }
    if (t < 10) bl[t] = fcb[t];
    __syncthreads();
    int n = blockIdx.x * 256 + t;
    if (n >= NN) return;
    const uint4* row = (const uint4*)(hbf + (size_t)n * FEAT);
    float lg[10];
    #pragma unroll
    for (int c = 0; c < 10; ++c) lg[c] = bl[c];
    #pragma unroll 4
    for (int k8 = 0; k8 < 16; ++k8) {
        uint4 u = row[k8];
        float x0 = bf_lo(u.x), x1 = bf_hi(u.x), x2 = bf_lo(u.y), x3 = bf_hi(u.y);
        float x4 = bf_lo(u.z), x5 = bf_hi(u.z), x6 = bf_lo(u.w), x7 = bf_hi(u.w);
        #pragma unroll
        for (int c = 0; c < 10; ++c) {
            const float* wr = &WT[c][k8 * 8];
            float4 wa = *(const float4*)(wr);
            float4 wb = *(const float4*)(wr + 4);
            float acc = fmaf(x0, wa.x, fmaf(x1, wa.y, fmaf(x2, wa.z, x3 * wa.w)));
            acc = fmaf(x4, wb.x, fmaf(x5, wb.y, fmaf(x6, wb.z, fmaf(x7, wb.w, acc))));
            lg[c] += acc;
        }
    }
    float mx = lg[0];
    #pragma unroll
    for (int c = 1; c < 10; ++c) mx = fmaxf(mx, lg[c]);
    float se = 0.f;
    #pragma unroll
    for (int c = 0; c < 10; ++c) se += __expf(lg[c] - mx);
    float lse = mx + __logf(se);
    float2* op = (float2*)(out + (size_t)n * 10);
    #pragma unroll
    for (int c = 0; c < 5; ++c)
        op[c] = make_float2(lg[2*c] - lse, lg[2*c + 1] - lse);
}

extern "C" void kernel_launch(void* const* d_in, const int* in_sizes, int n_in,
                              void* d_out, int out_size, void* d_ws, size_t ws_size,
                              hipStream_t stream)
{
    const float* x   = (const float*)d_in[0];
    const int*   ei  = (const int*)d_in[1];
    const float* W[3]   = {(const float*)d_in[2], (const float*)d_in[6],  (const float*)d_in[10]};
    const float* asr[3] = {(const float*)d_in[3], (const float*)d_in[7],  (const float*)d_in[11]};
    const float* ads[3] = {(const float*)d_in[4], (const float*)d_in[8],  (const float*)d_in[12]};
    const float* bs[3]  = {(const float*)d_in[5], (const float*)d_in[9],  (const float*)d_in[13]};
    const float* fcW = (const float*)d_in[14];
    const float* fcb = (const float*)d_in[15];
    const int E  = in_sizes[1] / 2;
    const int EP = E + NN;

    // workspace layout
    ushort* xbf  = (ushort*)d_ws;                      // [NN*FEAT] bf16 (layer-0 in)
    ushort* hbf  = xbf + (size_t)NN * FEAT;            // [NN*FEAT] bf16 (gemm out)
    ushort* ybf  = hbf + (size_t)NN * FEAT;            // [NN*FEAT] bf16 (aggr out)
    float* als   = (float*)(ybf + (size_t)NN * FEAT);  // [NN*4]
    float* ald   = als + (size_t)NN * NHEAD;           // [NN*4]
    int* row_ptr = (int*)(ald + (size_t)NN * NHEAD);   // [NN+1]
    int* bsize   = row_ptr + NN + 1;                   // [NBUCK]
    int* bbase   = bsize + NBUCK;                      // [NBUCK+1]
    int* bcursor = bbase + NBUCK + 1;                  // [NBUCK]
    int2* pairs  = (int2*)(bcursor + NBUCK);           // [EP]
    int* colidx  = (int*)(pairs + (size_t)EP);         // [EP]

    // ---- CSR build (once; graph is layer-invariant) ----
    zero_small_kernel<<<1, 256, 0, stream>>>(bsize);
    bucket_hist_kernel<<<1024, 256, 0, stream>>>(ei, E, bsize);
    bucket_scan_kernel<<<1, 64, 0, stream>>>(bsize, bbase, bcursor);
    phaseA_bin_kernel<<<(EP + 256*PA_EPT - 1) / (256*PA_EPT), 256, 0, stream>>>(ei, E, bcursor, pairs);
    phaseB_kernel<<<NBUCK, 256, 0, stream>>>(pairs, bbase, row_ptr, colidx, EP);

    convert_bf_kernel<<<(NN * FEAT / 4 + 255) / 256, 256, 0, stream>>>(x, xbf);

    const ushort* fin = xbf;
    for (int l = 0; l < 3; ++l) {
        gemm_mfma_kernel<<<512, 256, 0, stream>>>(fin, W[l], asr[l], ads[l], hbf, als, ald);
        aggr_csr_kernel<<<(NN + 15) / 16, 256, 0, stream>>>(row_ptr, colidx, hbf, als, ald, bs[l], ybf);
        fin = ybf;
    }
    fc_kernel<<<(NN + 255) / 256, 256, 0, stream>>>(ybf, fcW, fcb, (float*)d_out);
}